// Round 3
// baseline (4237.552 us; speedup 1.0000x reference)
//
#include <hip/hip_runtime.h>

// ---------------- common helpers ----------------
typedef short bf16x8 __attribute__((ext_vector_type(8)));
typedef float f32x4 __attribute__((ext_vector_type(4)));
typedef long long ll;

__device__ __forceinline__ unsigned short f2bf(float f) {
    union { float f; unsigned u; } v; v.f = f;
    unsigned u = v.u;
    unsigned r = (u + 0x7FFFu + ((u >> 16) & 1u)) >> 16;
    return (unsigned short)r;
}
__device__ __forceinline__ float bf2f(unsigned short h) {
    union { unsigned u; float f; } v; v.u = ((unsigned)h) << 16; return v.f;
}

// ---------------- generic bf16 MFMA GEMM ----------------
// C[M,N] = alpha * A[M,K] @ Bt[N,K]^T   (both operands bf16 row-major, fp32 acc)
// mode 0: fp32 store (+optional residual res[M,N])
// mode 1: bf16 store
// mode 2: bf16 store, zero where row==col (G build)
// mode 3: LCA update: un = u + 0.1*(bb - acc - u); u=un; C(bf16) = relu(un-0.1)
// causal: skip blocks with n0 > m0 (scores upper triangle)
//
// K-loop (R3): Tensile-style pipeline. Staging goes global->VGPR->ds_write
// instead of global_load_lds: register-destined global loads may legally
// stay in flight ACROSS s_barrier (only LDS writes must drain), so the
// barrier stops exposing load latency. R2's global_load_lds variant forced
// vmcnt(0) at every barrier (loads write LDS) -> MfmaUtil stuck at 22%.
// Loads for tile i+2 are issued at iter i and consumed (ds_write) at iter
// i+1 -> one full iteration of slack.
__global__ __launch_bounds__(256) void gemm_bf16(
    const unsigned short* __restrict__ A, ll lda, ll sAz,
    const unsigned short* __restrict__ B, ll ldb, ll sBz,
    void* __restrict__ C, ll ldc, ll sCz,
    int M, int N, int K,
    float alpha, int mode, int causal,
    const float* __restrict__ res,
    float* __restrict__ uu, const float* __restrict__ bbp)
{
    __shared__ unsigned short sA[2][4096];  // 128 rows x 32 (swizzled 16B chunks)
    __shared__ unsigned short sB[2][4096];
    const int n0 = blockIdx.x * 128;
    const int m0 = blockIdx.y * 128;
    if (causal && n0 > m0) return;
    const int z = blockIdx.z;

    const unsigned short* Ab = A + (ll)z * sAz + (ll)m0 * lda;
    const unsigned short* Bb = B + (ll)z * sBz + (ll)n0 * ldb;

    const int t    = threadIdx.x;
    const int lane = t & 63;
    const int w    = t >> 6, wm = w >> 1, wn = w & 1;
    const int m16  = lane & 15, quad = lane >> 4;

    // staging: thread t handles 16B chunk (t&3)^swz of row t>>2 / row t>>2+64
    const int r0 = t >> 2, cs = t & 3;
    const int r1 = r0 + 64;
    const int c0 = cs ^ ((r0 >> 1) & 3);
    const int c1 = cs ^ ((r1 >> 1) & 3);
    const ll a_off0 = (ll)r0 * lda + c0 * 8;
    const ll a_off1 = (ll)r1 * lda + c1 * 8;
    const ll b_off0 = (ll)r0 * ldb + c0 * 8;
    const ll b_off1 = (ll)r1 * ldb + c1 * 8;
    const int dst = t * 8;  // shorts; byte offset t*16, 16B-aligned

    // compute-phase LDS offsets (same swizzle)
    int aoff[4], boff[4];
#pragma unroll
    for (int mi = 0; mi < 4; mi++) {
        int rr = wm * 64 + mi * 16 + m16;
        aoff[mi] = rr * 32 + ((quad ^ ((rr >> 1) & 3)) << 3);
    }
#pragma unroll
    for (int ni = 0; ni < 4; ni++) {
        int rr = wn * 64 + ni * 16 + m16;
        boff[ni] = rr * 32 + ((quad ^ ((rr >> 1) & 3)) << 3);
    }

    f32x4 acc[4][4];
#pragma unroll
    for (int i = 0; i < 4; i++)
#pragma unroll
        for (int j = 0; j < 4; j++) acc[i][j] = (f32x4){0.f, 0.f, 0.f, 0.f};

    // prologue: tile 0 -> LDS[0] (one exposed load), tile 1 -> regs
    int4 ra0 = *(const int4*)(Ab + a_off0);
    int4 ra1 = *(const int4*)(Ab + a_off1);
    int4 rb0 = *(const int4*)(Bb + b_off0);
    int4 rb1 = *(const int4*)(Bb + b_off1);
    *(int4*)(sA[0] + dst)        = ra0;
    *(int4*)(sA[0] + 2048 + dst) = ra1;
    *(int4*)(sB[0] + dst)        = rb0;
    *(int4*)(sB[0] + 2048 + dst) = rb1;
    if (32 < K) {
        ra0 = *(const int4*)(Ab + a_off0 + 32);
        ra1 = *(const int4*)(Ab + a_off1 + 32);
        rb0 = *(const int4*)(Bb + b_off0 + 32);
        rb1 = *(const int4*)(Bb + b_off1 + 32);
    }
    __syncthreads();

    for (int kt = 0; kt < K; kt += 32) {
        const int cur = (kt >> 5) & 1, nxt = cur ^ 1;
        int4 na0, na1, nb0, nb1;
        // issue loads for tile kt+2 first (more slack before their use)
        if (kt + 64 < K) {
            na0 = *(const int4*)(Ab + a_off0 + kt + 64);
            na1 = *(const int4*)(Ab + a_off1 + kt + 64);
            nb0 = *(const int4*)(Bb + b_off0 + kt + 64);
            nb1 = *(const int4*)(Bb + b_off1 + kt + 64);
        }
        // ds_write tile kt+1 (regs loaded one full iteration ago)
        if (kt + 32 < K) {
            *(int4*)(sA[nxt] + dst)        = ra0;
            *(int4*)(sA[nxt] + 2048 + dst) = ra1;
            *(int4*)(sB[nxt] + dst)        = rb0;
            *(int4*)(sB[nxt] + 2048 + dst) = rb1;
        }
        // compute tile kt from LDS[cur]
        bf16x8 af[4], bg[4];
#pragma unroll
        for (int mi = 0; mi < 4; mi++) af[mi] = *(const bf16x8*)(sA[cur] + aoff[mi]);
#pragma unroll
        for (int ni = 0; ni < 4; ni++) bg[ni] = *(const bf16x8*)(sB[cur] + boff[ni]);
#pragma unroll
        for (int mi = 0; mi < 4; mi++)
#pragma unroll
            for (int ni = 0; ni < 4; ni++)
                acc[mi][ni] = __builtin_amdgcn_mfma_f32_16x16x32_bf16(
                    af[mi], bg[ni], acc[mi][ni], 0, 0, 0);
        __syncthreads();
        ra0 = na0; ra1 = na1; rb0 = nb0; rb1 = nb1;
    }

    const ll czoff = (ll)z * sCz;
#pragma unroll
    for (int mi = 0; mi < 4; mi++) {
#pragma unroll
        for (int ni = 0; ni < 4; ni++) {
#pragma unroll
            for (int r = 0; r < 4; r++) {
                int row = m0 + wm * 64 + mi * 16 + quad * 4 + r;
                int col = n0 + wn * 64 + ni * 16 + m16;
                ll idx = czoff + (ll)row * ldc + col;
                float v = acc[mi][ni][r] * alpha;
                if (mode == 0) {
                    ((float*)C)[idx] = res ? (v + res[idx]) : v;
                } else if (mode == 1) {
                    ((unsigned short*)C)[idx] = f2bf(v);
                } else if (mode == 2) {
                    ((unsigned short*)C)[idx] = (row == col) ? (unsigned short)0 : f2bf(v);
                } else {
                    float un = uu[idx] + 0.1f * (bbp[idx] - v - uu[idx]);
                    uu[idx] = un;
                    ((unsigned short*)C)[idx] = f2bf(fmaxf(un - 0.1f, 0.0f));
                }
            }
        }
    }
}

// ---------------- elementwise / transform kernels ----------------

// fp32 [R,C] -> bf16 [C,R] (transpose + convert)
__global__ void wtrans_k(const float* __restrict__ in, unsigned short* __restrict__ out,
                         int R, int C) {
    __shared__ float tile[32][33];
    ll bx = (ll)blockIdx.x * 32, by = (ll)blockIdx.y * 32;
    int tx = threadIdx.x & 31, ty = threadIdx.x >> 5;
#pragma unroll
    for (int i = ty; i < 32; i += 8) tile[i][tx] = in[(by + i) * C + bx + tx];
    __syncthreads();
#pragma unroll
    for (int i = ty; i < 32; i += 8) out[(bx + i) * R + by + tx] = f2bf(tile[tx][i]);
}

// fp32 -> bf16, 4/thread
__global__ void conv4_k(const float* __restrict__ in, unsigned short* __restrict__ out, ll n) {
    ll i = ((ll)blockIdx.x * 256 + threadIdx.x) * 4;
    if (i >= n) return;
    float4 v = *(const float4*)(in + i);
    out[i] = f2bf(v.x); out[i + 1] = f2bf(v.y); out[i + 2] = f2bf(v.z); out[i + 3] = f2bf(v.w);
}

// rmsnorm row of 2048, fp32 in -> bf16 out
__global__ void rmsnorm_k(const float* __restrict__ in, const float* __restrict__ w,
                          unsigned short* __restrict__ out) {
    int row = blockIdx.x, t = threadIdx.x;
    const float* x = in + (ll)row * 2048;
    float v[8]; float s = 0.f;
#pragma unroll
    for (int i = 0; i < 8; i++) { v[i] = x[t + i * 256]; s += v[i] * v[i]; }
#pragma unroll
    for (int o = 32; o > 0; o >>= 1) s += __shfl_xor(s, o, 64);
    __shared__ float rs[4];
    if ((t & 63) == 0) rs[t >> 6] = s;
    __syncthreads();
    s = (rs[0] + rs[1] + rs[2] + rs[3]) * (1.0f / 2048.0f);
    float sc = rsqrtf(s + 1e-6f);
    unsigned short* o_ = out + (ll)row * 2048;
#pragma unroll
    for (int i = 0; i < 8; i++) o_[t + i * 256] = f2bf(v[i] * sc * w[t + i * 256]);
}

// in-place RoPE on bf16 q,k  [4096 rows][16 heads][128]
__global__ void rope_k(unsigned short* __restrict__ q, unsigned short* __restrict__ k) {
    int idx = blockIdx.x * 256 + threadIdx.x;      // B*S*H*64 = 4,194,304
    int j = idx & 63;
    int h = (idx >> 6) & 15;
    int row = idx >> 10;                            // 0..4095 (= b*2048+s)
    int s = row & 2047;
    float f = __expf(-(float)j * 0.14391156831212783f);  // ln(10000)/64
    float ang = (float)s * f;
    float sn, cs;
    sincosf(ang, &sn, &cs);
    ll base = (ll)row * 2048 + h * 128 + j;
    float x1 = bf2f(q[base]), x2 = bf2f(q[base + 64]);
    q[base]      = f2bf(x1 * cs - x2 * sn);
    q[base + 64] = f2bf(x2 * cs + x1 * sn);
    x1 = bf2f(k[base]); x2 = bf2f(k[base + 64]);
    k[base]      = f2bf(x1 * cs - x2 * sn);
    k[base + 64] = f2bf(x2 * cs + x1 * sn);
}

// V [4096,(h,128)] bf16 -> VT [b,h][128][2048]
__global__ void vtrans_k(const unsigned short* __restrict__ in, unsigned short* __restrict__ out) {
    __shared__ unsigned short tile[32][33];
    int z = blockIdx.z, b = z >> 4, h = z & 15;
    const unsigned short* ib = in + (ll)b * 4194304 + h * 128;
    unsigned short* ob = out + (ll)z * 262144;
    int bx = blockIdx.x * 32, by = blockIdx.y * 32;
    int tx = threadIdx.x & 31, ty = threadIdx.x >> 5;
#pragma unroll
    for (int i = ty; i < 32; i += 8) tile[i][tx] = ib[(ll)(by + i) * 2048 + bx + tx];
    __syncthreads();
#pragma unroll
    for (int i = ty; i < 32; i += 8) ob[(ll)(bx + i) * 2048 + by + tx] = tile[tx][i];
}

// causal softmax, in-place on bf16 scores [z][2048][2048]
__global__ void softmax_k(unsigned short* __restrict__ sc) {
    int q = blockIdx.x, z = blockIdx.y, t = threadIdx.x;
    unsigned short* row = sc + (ll)z * 4194304 + (ll)q * 2048;
    float x[8]; float m = -1e30f;
#pragma unroll
    for (int i = 0; i < 8; i++) {
        int kk = t + i * 256;
        x[i] = (kk <= q) ? bf2f(row[kk]) : -1e30f;
        m = fmaxf(m, x[i]);
    }
#pragma unroll
    for (int o = 32; o > 0; o >>= 1) m = fmaxf(m, __shfl_xor(m, o, 64));
    __shared__ float rm[4];
    if ((t & 63) == 0) rm[t >> 6] = m;
    __syncthreads();
    m = fmaxf(fmaxf(rm[0], rm[1]), fmaxf(rm[2], rm[3]));
    float s = 0.f;
#pragma unroll
    for (int i = 0; i < 8; i++) {
        int kk = t + i * 256;
        float e = (kk <= q) ? __expf(x[i] - m) : 0.0f;
        x[i] = e; s += e;
    }
#pragma unroll
    for (int o = 32; o > 0; o >>= 1) s += __shfl_xor(s, o, 64);
    __shared__ float rsum[4];
    if ((t & 63) == 0) rsum[t >> 6] = s;
    __syncthreads();
    s = rsum[0] + rsum[1] + rsum[2] + rsum[3];
    float inv = 1.0f / s;
#pragma unroll
    for (int i = 0; i < 8; i++) row[t + i * 256] = f2bf(x[i] * inv);
}

// u = 0.1*b ; a = relu(u-0.1) (step 1 of LCA, since a(u=0)=0)
__global__ void lca_init_k(const float* __restrict__ b, float* __restrict__ u,
                           unsigned short* __restrict__ a) {
    ll i = ((ll)blockIdx.x * 256 + threadIdx.x) * 4;
    float4 bv = *(const float4*)(b + i);
    float4 uv; uv.x = 0.1f * bv.x; uv.y = 0.1f * bv.y; uv.z = 0.1f * bv.z; uv.w = 0.1f * bv.w;
    *(float4*)(u + i) = uv;
    a[i]     = f2bf(fmaxf(uv.x - 0.1f, 0.f));
    a[i + 1] = f2bf(fmaxf(uv.y - 0.1f, 0.f));
    a[i + 2] = f2bf(fmaxf(uv.z - 0.1f, 0.f));
    a[i + 3] = f2bf(fmaxf(uv.w - 0.1f, 0.f));
}

// g = silu(g) * up  (bf16 in/out)
__global__ void swiglu_k(unsigned short* __restrict__ g, const unsigned short* __restrict__ u) {
    ll i = ((ll)blockIdx.x * 256 + threadIdx.x) * 4;
#pragma unroll
    for (int j = 0; j < 4; j++) {
        float x = bf2f(g[i + j]);
        float y = bf2f(u[i + j]);
        float sil = x / (1.0f + __expf(-x));
        g[i + j] = f2bf(sil * y);
    }
}

// ---------------- host orchestration ----------------
extern "C" void kernel_launch(void* const* d_in, const int* in_sizes, int n_in,
                              void* d_out, int out_size, void* d_ws, size_t ws_size,
                              hipStream_t stream) {
    (void)in_sizes; (void)n_in; (void)out_size; (void)ws_size;
    const float* X        = (const float*)d_in[0];   // [2,2048,2048]
    const float* wln_in   = (const float*)d_in[1];
    const float* wln_lca  = (const float*)d_in[2];
    const float* wln_post = (const float*)d_in[3];
    const float* Wq   = (const float*)d_in[4];
    const float* Wk   = (const float*)d_in[5];
    const float* Wv   = (const float*)d_in[6];
    const float* Wo   = (const float*)d_in[7];
    const float* Wlca = (const float*)d_in[8];       // [2048,4096]
    const float* Wg   = (const float*)d_in[9];       // [2048,8192]
    const float* Wu   = (const float*)d_in[10];
    const float* Wd   = (const float*)d_in[11];      // [8192,2048]
    float* out = (float*)d_out;

    char* ws = (char*)d_ws;
    // region W1 (qkvo transposed; reused for WgT in MLP phase)
    unsigned short* WqT = (unsigned short*)(ws);
    unsigned short* WkT = WqT + 4194304;
    unsigned short* WvT = WqT + 2 * 4194304;
    unsigned short* WoT = WqT + 3 * 4194304;
    unsigned short* WgT = WqT;
    // region W2 (W_lca both orientations; reused for WuT)
    unsigned short* WlcaT = (unsigned short*)(ws + 33554432);  // [4096,2048]
    unsigned short* Wlcab = WlcaT + 8388608;                   // [2048,4096] direct
    unsigned short* WuT   = WlcaT;
    // h_bf (normed activations, bf16)
    unsigned short* h_bf = (unsigned short*)(ws + 67108864);
    // overlaid pool
    char* pool = ws + 83886080;
    unsigned short* qb     = (unsigned short*)(pool);
    unsigned short* kb     = (unsigned short*)(pool + 16777216);
    unsigned short* vb     = (unsigned short*)(pool + 33554432);
    unsigned short* VT     = (unsigned short*)(pool + 50331648);
    unsigned short* attn   = (unsigned short*)(pool + 67108864);
    unsigned short* scores = (unsigned short*)(pool + 83886080);   // 8 heads * S*S bf16
    float* h1              = (float*)(pool + 150994944);
    float* bbuf            = (float*)(pool);                        // LCA phase
    float* ubuf            = (float*)(pool + 67108864);
    unsigned short* a0     = (unsigned short*)(pool + 134217728);
    unsigned short* a1     = (unsigned short*)(pool + 167772160);
    unsigned short* Gbf    = (unsigned short*)(pool + 201326592);
    float* h2              = (float*)(pool + 134217728);            // a0 slot (MLP phase)
    unsigned short* gate   = (unsigned short*)(pool);
    unsigned short* up     = (unsigned short*)(pool + 67108864);
    unsigned short* WdT    = (unsigned short*)(pool + 201326592);   // G slot

    dim3 blk(256);
    auto gemm = [&](const unsigned short* A, ll lda, ll sAz,
                    const unsigned short* Bt, ll ldb, ll sBz,
                    void* C, ll ldc, ll sCz,
                    int M, int N, int K, int Z,
                    float alpha, int mode, int causal,
                    const float* res, float* uu, const float* bbp) {
        dim3 g(N / 128, M / 128, Z);
        gemm_bf16<<<g, blk, 0, stream>>>(A, lda, sAz, Bt, ldb, sBz, C, ldc, sCz,
                                         M, N, K, alpha, mode, causal, res, uu, bbp);
    };

    // --- weight prep (attention + LCA weights) ---
    wtrans_k<<<dim3(64, 64), blk, 0, stream>>>(Wq, WqT, 2048, 2048);
    wtrans_k<<<dim3(64, 64), blk, 0, stream>>>(Wk, WkT, 2048, 2048);
    wtrans_k<<<dim3(64, 64), blk, 0, stream>>>(Wv, WvT, 2048, 2048);
    wtrans_k<<<dim3(64, 64), blk, 0, stream>>>(Wo, WoT, 2048, 2048);
    wtrans_k<<<dim3(128, 64), blk, 0, stream>>>(Wlca, WlcaT, 2048, 4096);
    conv4_k<<<8192, blk, 0, stream>>>(Wlca, Wlcab, 8388608LL);

    // --- attention ---
    rmsnorm_k<<<4096, blk, 0, stream>>>(X, wln_in, h_bf);
    gemm(h_bf, 2048, 0, WqT, 2048, 0, qb, 2048, 0, 4096, 2048, 2048, 1, 1.f, 1, 0, nullptr, nullptr, nullptr);
    gemm(h_bf, 2048, 0, WkT, 2048, 0, kb, 2048, 0, 4096, 2048, 2048, 1, 1.f, 1, 0, nullptr, nullptr, nullptr);
    gemm(h_bf, 2048, 0, WvT, 2048, 0, vb, 2048, 0, 4096, 2048, 2048, 1, 1.f, 1, 0, nullptr, nullptr, nullptr);
    rope_k<<<16384, blk, 0, stream>>>(qb, kb);
    vtrans_k<<<dim3(4, 64, 32), blk, 0, stream>>>(vb, VT);
    for (int c = 0; c < 4; c++) {
        int b = c >> 1, h0 = (c & 1) * 8;
        const unsigned short* qbase = qb + (ll)b * 4194304 + h0 * 128;
        const unsigned short* kbase = kb + (ll)b * 4194304 + h0 * 128;
        gemm(qbase, 2048, 128, kbase, 2048, 128, scores, 2048, 4194304LL,
             2048, 2048, 128, 8, 0.08838834764831845f, 1, 1, nullptr, nullptr, nullptr);
        softmax_k<<<dim3(2048, 8), blk, 0, stream>>>(scores);
        const unsigned short* vtb = VT + (ll)(b * 16 + h0) * 262144;
        unsigned short* ab = attn + (ll)b * 4194304 + h0 * 128;
        gemm(scores, 2048, 4194304LL, vtb, 2048, 262144LL, ab, 2048, 128,
             2048, 128, 2048, 8, 1.f, 1, 0, nullptr, nullptr, nullptr);
    }
    gemm(attn, 2048, 0, WoT, 2048, 0, h1, 2048, 0, 4096, 2048, 2048, 1, 1.f, 0, 0, X, nullptr, nullptr);

    // --- LCA ---
    rmsnorm_k<<<4096, blk, 0, stream>>>(h1, wln_lca, h_bf);
    gemm(WlcaT, 2048, 0, WlcaT, 2048, 0, Gbf, 4096, 0, 4096, 4096, 2048, 1, 1.f, 2, 0, nullptr, nullptr, nullptr);
    gemm(h_bf, 2048, 0, WlcaT, 2048, 0, bbuf, 4096, 0, 4096, 4096, 2048, 1, 1.f, 0, 0, nullptr, nullptr, nullptr);
    lca_init_k<<<16384, blk, 0, stream>>>(bbuf, ubuf, a0);
    unsigned short* acur = a0; unsigned short* anext = a1;
    for (int i = 0; i < 9; i++) {
        gemm(acur, 4096, 0, Gbf, 4096, 0, anext, 4096, 0, 4096, 4096, 4096, 1,
             1.f, 3, 0, nullptr, ubuf, bbuf);
        unsigned short* tmp = acur; acur = anext; anext = tmp;
    }
    gemm(acur, 4096, 0, Wlcab, 4096, 0, h2, 2048, 0, 4096, 2048, 4096, 1, 1.f, 0, 0, nullptr, nullptr, nullptr);

    // --- MLP ---
    wtrans_k<<<dim3(256, 64), blk, 0, stream>>>(Wg, WgT, 2048, 8192);
    wtrans_k<<<dim3(256, 64), blk, 0, stream>>>(Wu, WuT, 2048, 8192);
    wtrans_k<<<dim3(64, 256), blk, 0, stream>>>(Wd, WdT, 8192, 2048);
    rmsnorm_k<<<4096, blk, 0, stream>>>(h2, wln_post, h_bf);
    gemm(h_bf, 2048, 0, WgT, 2048, 0, gate, 8192, 0, 4096, 8192, 2048, 1, 1.f, 1, 0, nullptr, nullptr, nullptr);
    gemm(h_bf, 2048, 0, WuT, 2048, 0, up, 8192, 0, 4096, 8192, 2048, 1, 1.f, 1, 0, nullptr, nullptr, nullptr);
    swiglu_k<<<32768, blk, 0, stream>>>(gate, up);
    gemm(gate, 8192, 0, WdT, 8192, 0, out, 2048, 0, 4096, 2048, 8192, 1, 1.f, 0, 0, h2, nullptr, nullptr);
}

// Round 4
// 3340.566 us; speedup vs baseline: 1.2685x; 1.2685x over previous
//
#include <hip/hip_runtime.h>
#include <hip/hip_fp8.h>

// ---------------- common helpers ----------------
typedef short bf16x8 __attribute__((ext_vector_type(8)));
typedef float f32x4 __attribute__((ext_vector_type(4)));
typedef long long ll;

__device__ __forceinline__ unsigned short f2bf(float f) {
    union { float f; unsigned u; } v; v.f = f;
    unsigned u = v.u;
    unsigned r = (u + 0x7FFFu + ((u >> 16) & 1u)) >> 16;
    return (unsigned short)r;
}
__device__ __forceinline__ float bf2f(unsigned short h) {
    union { unsigned u; float f; } v; v.u = ((unsigned)h) << 16; return v.f;
}
__device__ __forceinline__ unsigned char f2fp8(float f) {
    __hip_fp8_e4m3 q(f);
    return (unsigned char)q.__x;
}

typedef const __attribute__((address_space(1))) void gas_void;
typedef __attribute__((address_space(3))) void las_void;
__device__ __forceinline__ void gll16(const void* g, void* l) {
    __builtin_amdgcn_global_load_lds((gas_void*)g, (las_void*)l, 16, 0, 0);
}

// ---------------- generic bf16 MFMA GEMM (R2 K-loop: gll16 dbuf, 1 barrier) ----------------
// C[M,N] = alpha * A[M,K] @ Bt[N,K]^T
// mode 0: fp32 store (+optional residual res[M,N])
// mode 1: bf16 store
// mode 2: fp8 store of alpha*acc, zero where row==col (G build, pre-scaled by alpha=16)
// causal: skip blocks with n0 > m0
__global__ __launch_bounds__(256) void gemm_bf16(
    const unsigned short* __restrict__ A, ll lda, ll sAz,
    const unsigned short* __restrict__ B, ll ldb, ll sBz,
    void* __restrict__ C, ll ldc, ll sCz,
    int M, int N, int K,
    float alpha, int mode, int causal,
    const float* __restrict__ res)
{
    __shared__ unsigned short sA[2][4096];
    __shared__ unsigned short sB[2][4096];
    const int n0 = blockIdx.x * 128;
    const int m0 = blockIdx.y * 128;
    if (causal && n0 > m0) return;
    const int z = blockIdx.z;

    const unsigned short* Ab = A + (ll)z * sAz + (ll)m0 * lda;
    const unsigned short* Bb = B + (ll)z * sBz + (ll)n0 * ldb;

    const int t    = threadIdx.x;
    const int lane = t & 63;
    const int w    = t >> 6, wm = w >> 1, wn = w & 1;
    const int m16  = lane & 15, quad = lane >> 4;

    const int r0 = t >> 2, cs = t & 3;
    const int r1 = r0 + 64;
    const int c0 = cs ^ ((r0 >> 1) & 3);
    const int c1 = cs ^ ((r1 >> 1) & 3);
    const ll a_off0 = (ll)r0 * lda + c0 * 8;
    const ll a_off1 = (ll)r1 * lda + c1 * 8;
    const ll b_off0 = (ll)r0 * ldb + c0 * 8;
    const ll b_off1 = (ll)r1 * ldb + c1 * 8;
    const int dst = t * 8;

    int aoff[4], boff[4];
#pragma unroll
    for (int mi = 0; mi < 4; mi++) {
        int rr = wm * 64 + mi * 16 + m16;
        aoff[mi] = rr * 32 + ((quad ^ ((rr >> 1) & 3)) << 3);
    }
#pragma unroll
    for (int ni = 0; ni < 4; ni++) {
        int rr = wn * 64 + ni * 16 + m16;
        boff[ni] = rr * 32 + ((quad ^ ((rr >> 1) & 3)) << 3);
    }

    f32x4 acc[4][4];
#pragma unroll
    for (int i = 0; i < 4; i++)
#pragma unroll
        for (int j = 0; j < 4; j++) acc[i][j] = (f32x4){0.f, 0.f, 0.f, 0.f};

    gll16(Ab + a_off0, sA[0] + dst);
    gll16(Ab + a_off1, sA[0] + 2048 + dst);
    gll16(Bb + b_off0, sB[0] + dst);
    gll16(Bb + b_off1, sB[0] + 2048 + dst);
    __syncthreads();

    for (int kt = 0; kt < K; kt += 32) {
        const int cur = (kt >> 5) & 1;
        if (kt + 32 < K) {
            const int nxt = cur ^ 1;
            gll16(Ab + a_off0 + kt + 32, sA[nxt] + dst);
            gll16(Ab + a_off1 + kt + 32, sA[nxt] + 2048 + dst);
            gll16(Bb + b_off0 + kt + 32, sB[nxt] + dst);
            gll16(Bb + b_off1 + kt + 32, sB[nxt] + 2048 + dst);
        }
        bf16x8 af[4], bg[4];
#pragma unroll
        for (int mi = 0; mi < 4; mi++) af[mi] = *(const bf16x8*)(sA[cur] + aoff[mi]);
#pragma unroll
        for (int ni = 0; ni < 4; ni++) bg[ni] = *(const bf16x8*)(sB[cur] + boff[ni]);
#pragma unroll
        for (int mi = 0; mi < 4; mi++)
#pragma unroll
            for (int ni = 0; ni < 4; ni++)
                acc[mi][ni] = __builtin_amdgcn_mfma_f32_16x16x32_bf16(
                    af[mi], bg[ni], acc[mi][ni], 0, 0, 0);
        __syncthreads();
    }

    const ll czoff = (ll)z * sCz;
#pragma unroll
    for (int mi = 0; mi < 4; mi++) {
#pragma unroll
        for (int ni = 0; ni < 4; ni++) {
#pragma unroll
            for (int r = 0; r < 4; r++) {
                int row = m0 + wm * 64 + mi * 16 + quad * 4 + r;
                int col = n0 + wn * 64 + ni * 16 + m16;
                ll idx = czoff + (ll)row * ldc + col;
                float v = acc[mi][ni][r] * alpha;
                if (mode == 0) {
                    ((float*)C)[idx] = res ? (v + res[idx]) : v;
                } else if (mode == 1) {
                    ((unsigned short*)C)[idx] = f2bf(v);
                } else {
                    ((unsigned char*)C)[idx] = (row == col) ? (unsigned char)0 : f2fp8(v);
                }
            }
        }
    }
}

// ---------------- fp8 MFMA GEMM for the LCA a@G chain ----------------
// acc = (a*8)[M,K] @ (G*16)[N,K]^T  (G symmetric so Bt = G); BK=64, dbuf gll16.
// Epilogue: v = alpha*acc (alpha=0.1/128 -> v = 0.1*aG);
//   un = 0.9*u + c - v; u(bf16) = un;  a' = relu(un-0.1)
//   mode 3: out fp8 = a'*8 (next chain step);  mode 4: out bf16 = a' (final)
__global__ __launch_bounds__(256) void gemm_fp8(
    const unsigned char* __restrict__ A, ll lda,
    const unsigned char* __restrict__ B, ll ldb,
    int M, int N, int K, float alpha, int mode,
    unsigned short* __restrict__ uu, const unsigned short* __restrict__ cc,
    void* __restrict__ Out)
{
    __shared__ unsigned char sA[2][8192];   // 128 rows x 64 B (swizzled 16B chunks)
    __shared__ unsigned char sB[2][8192];
    const int n0 = blockIdx.x * 128;
    const int m0 = blockIdx.y * 128;

    const unsigned char* Ab = A + (ll)m0 * lda;
    const unsigned char* Bb = B + (ll)n0 * ldb;

    const int t    = threadIdx.x;
    const int lane = t & 63;
    const int w    = t >> 6, wm = w >> 1, wn = w & 1;
    const int m16  = lane & 15, quad = lane >> 4;

    const int r0 = t >> 2, cs = t & 3;
    const int r1 = r0 + 64;
    const int c0 = cs ^ ((r0 >> 1) & 3);
    const int c1 = cs ^ ((r1 >> 1) & 3);
    const ll a_off0 = (ll)r0 * lda + c0 * 16;
    const ll a_off1 = (ll)r1 * lda + c1 * 16;
    const ll b_off0 = (ll)r0 * ldb + c0 * 16;
    const ll b_off1 = (ll)r1 * ldb + c1 * 16;
    const int dst = t * 16;

    // fragment byte offsets: row rr (64B), k-half kh: bytes [kh*32+quad*8, +8)
    int aoff[4][2], boff[4][2];
#pragma unroll
    for (int mi = 0; mi < 4; mi++) {
        int rr = wm * 64 + mi * 16 + m16;
#pragma unroll
        for (int kh = 0; kh < 2; kh++) {
            int ch = kh * 2 + (quad >> 1);
            aoff[mi][kh] = rr * 64 + ((ch ^ ((rr >> 1) & 3)) << 4) + ((quad & 1) << 3);
        }
    }
#pragma unroll
    for (int ni = 0; ni < 4; ni++) {
        int rr = wn * 64 + ni * 16 + m16;
#pragma unroll
        for (int kh = 0; kh < 2; kh++) {
            int ch = kh * 2 + (quad >> 1);
            boff[ni][kh] = rr * 64 + ((ch ^ ((rr >> 1) & 3)) << 4) + ((quad & 1) << 3);
        }
    }

    f32x4 acc[4][4];
#pragma unroll
    for (int i = 0; i < 4; i++)
#pragma unroll
        for (int j = 0; j < 4; j++) acc[i][j] = (f32x4){0.f, 0.f, 0.f, 0.f};

    gll16(Ab + a_off0, sA[0] + dst);
    gll16(Ab + a_off1, sA[0] + 4096 + dst);
    gll16(Bb + b_off0, sB[0] + dst);
    gll16(Bb + b_off1, sB[0] + 4096 + dst);
    __syncthreads();

    for (int kt = 0; kt < K; kt += 64) {
        const int cur = (kt >> 6) & 1;
        if (kt + 64 < K) {
            const int nxt = cur ^ 1;
            gll16(Ab + a_off0 + kt + 64, sA[nxt] + dst);
            gll16(Ab + a_off1 + kt + 64, sA[nxt] + 4096 + dst);
            gll16(Bb + b_off0 + kt + 64, sB[nxt] + dst);
            gll16(Bb + b_off1 + kt + 64, sB[nxt] + 4096 + dst);
        }
#pragma unroll
        for (int kh = 0; kh < 2; kh++) {
            long long af[4], bg[4];
#pragma unroll
            for (int mi = 0; mi < 4; mi++)
                af[mi] = *(const long long*)(sA[cur] + aoff[mi][kh]);
#pragma unroll
            for (int ni = 0; ni < 4; ni++)
                bg[ni] = *(const long long*)(sB[cur] + boff[ni][kh]);
#pragma unroll
            for (int mi = 0; mi < 4; mi++)
#pragma unroll
                for (int ni = 0; ni < 4; ni++)
                    acc[mi][ni] = __builtin_amdgcn_mfma_f32_16x16x32_fp8_fp8(
                        af[mi], bg[ni], acc[mi][ni], 0, 0, 0);
        }
        __syncthreads();
    }

#pragma unroll
    for (int mi = 0; mi < 4; mi++) {
#pragma unroll
        for (int ni = 0; ni < 4; ni++) {
#pragma unroll
            for (int r = 0; r < 4; r++) {
                int row = m0 + wm * 64 + mi * 16 + quad * 4 + r;
                int col = n0 + wn * 64 + ni * 16 + m16;
                ll idx = (ll)row * N + col;
                float v = acc[mi][ni][r] * alpha;
                float un = 0.9f * bf2f(uu[idx]) + bf2f(cc[idx]) - v;
                uu[idx] = f2bf(un);
                float a = fmaxf(un - 0.1f, 0.0f);
                if (mode == 3) ((unsigned char*)Out)[idx] = f2fp8(a * 8.0f);
                else           ((unsigned short*)Out)[idx] = f2bf(a);
            }
        }
    }
}

// ---------------- elementwise / transform kernels ----------------

// fp32 [R,C] -> bf16 [C,R] (transpose + convert)
__global__ void wtrans_k(const float* __restrict__ in, unsigned short* __restrict__ out,
                         int R, int C) {
    __shared__ float tile[32][33];
    ll bx = (ll)blockIdx.x * 32, by = (ll)blockIdx.y * 32;
    int tx = threadIdx.x & 31, ty = threadIdx.x >> 5;
#pragma unroll
    for (int i = ty; i < 32; i += 8) tile[i][tx] = in[(by + i) * C + bx + tx];
    __syncthreads();
#pragma unroll
    for (int i = ty; i < 32; i += 8) out[(bx + i) * R + by + tx] = f2bf(tile[tx][i]);
}

// fp32 -> bf16, 4/thread
__global__ void conv4_k(const float* __restrict__ in, unsigned short* __restrict__ out, ll n) {
    ll i = ((ll)blockIdx.x * 256 + threadIdx.x) * 4;
    if (i >= n) return;
    float4 v = *(const float4*)(in + i);
    out[i] = f2bf(v.x); out[i + 1] = f2bf(v.y); out[i + 2] = f2bf(v.z); out[i + 3] = f2bf(v.w);
}

// rmsnorm row of 2048, fp32 in -> bf16 out
__global__ void rmsnorm_k(const float* __restrict__ in, const float* __restrict__ w,
                          unsigned short* __restrict__ out) {
    int row = blockIdx.x, t = threadIdx.x;
    const float* x = in + (ll)row * 2048;
    float v[8]; float s = 0.f;
#pragma unroll
    for (int i = 0; i < 8; i++) { v[i] = x[t + i * 256]; s += v[i] * v[i]; }
#pragma unroll
    for (int o = 32; o > 0; o >>= 1) s += __shfl_xor(s, o, 64);
    __shared__ float rs[4];
    if ((t & 63) == 0) rs[t >> 6] = s;
    __syncthreads();
    s = (rs[0] + rs[1] + rs[2] + rs[3]) * (1.0f / 2048.0f);
    float sc = rsqrtf(s + 1e-6f);
    unsigned short* o_ = out + (ll)row * 2048;
#pragma unroll
    for (int i = 0; i < 8; i++) o_[t + i * 256] = f2bf(v[i] * sc * w[t + i * 256]);
}

// in-place RoPE on bf16 q,k  [4096 rows][16 heads][128]
__global__ void rope_k(unsigned short* __restrict__ q, unsigned short* __restrict__ k) {
    int idx = blockIdx.x * 256 + threadIdx.x;
    int j = idx & 63;
    int h = (idx >> 6) & 15;
    int row = idx >> 10;
    int s = row & 2047;
    float f = __expf(-(float)j * 0.14391156831212783f);
    float ang = (float)s * f;
    float sn, cs;
    sincosf(ang, &sn, &cs);
    ll base = (ll)row * 2048 + h * 128 + j;
    float x1 = bf2f(q[base]), x2 = bf2f(q[base + 64]);
    q[base]      = f2bf(x1 * cs - x2 * sn);
    q[base + 64] = f2bf(x2 * cs + x1 * sn);
    x1 = bf2f(k[base]); x2 = bf2f(k[base + 64]);
    k[base]      = f2bf(x1 * cs - x2 * sn);
    k[base + 64] = f2bf(x2 * cs + x1 * sn);
}

// V [4096,(h,128)] bf16 -> VT [b,h][128][2048]
__global__ void vtrans_k(const unsigned short* __restrict__ in, unsigned short* __restrict__ out) {
    __shared__ unsigned short tile[32][33];
    int z = blockIdx.z, b = z >> 4, h = z & 15;
    const unsigned short* ib = in + (ll)b * 4194304 + h * 128;
    unsigned short* ob = out + (ll)z * 262144;
    int bx = blockIdx.x * 32, by = blockIdx.y * 32;
    int tx = threadIdx.x & 31, ty = threadIdx.x >> 5;
#pragma unroll
    for (int i = ty; i < 32; i += 8) tile[i][tx] = ib[(ll)(by + i) * 2048 + bx + tx];
    __syncthreads();
#pragma unroll
    for (int i = ty; i < 32; i += 8) ob[(ll)(bx + i) * 2048 + by + tx] = tile[tx][i];
}

// causal softmax, in-place on bf16 scores [z][2048][2048]
__global__ void softmax_k(unsigned short* __restrict__ sc) {
    int q = blockIdx.x, z = blockIdx.y, t = threadIdx.x;
    unsigned short* row = sc + (ll)z * 4194304 + (ll)q * 2048;
    float x[8]; float m = -1e30f;
#pragma unroll
    for (int i = 0; i < 8; i++) {
        int kk = t + i * 256;
        x[i] = (kk <= q) ? bf2f(row[kk]) : -1e30f;
        m = fmaxf(m, x[i]);
    }
#pragma unroll
    for (int o = 32; o > 0; o >>= 1) m = fmaxf(m, __shfl_xor(m, o, 64));
    __shared__ float rm[4];
    if ((t & 63) == 0) rm[t >> 6] = m;
    __syncthreads();
    m = fmaxf(fmaxf(rm[0], rm[1]), fmaxf(rm[2], rm[3]));
    float s = 0.f;
#pragma unroll
    for (int i = 0; i < 8; i++) {
        int kk = t + i * 256;
        float e = (kk <= q) ? __expf(x[i] - m) : 0.0f;
        x[i] = e; s += e;
    }
#pragma unroll
    for (int o = 32; o > 0; o >>= 1) s += __shfl_xor(s, o, 64);
    __shared__ float rsum[4];
    if ((t & 63) == 0) rsum[t >> 6] = s;
    __syncthreads();
    s = rsum[0] + rsum[1] + rsum[2] + rsum[3];
    float inv = 1.0f / s;
#pragma unroll
    for (int i = 0; i < 8; i++) row[t + i * 256] = f2bf(x[i] * inv);
}

// LCA step 1: u1 = c (=0.1*b, bf16); a1 = fp8(relu(c-0.1)*8)
__global__ void lca_init_k(const unsigned short* __restrict__ c, unsigned short* __restrict__ u,
                           unsigned char* __restrict__ a) {
    ll i = ((ll)blockIdx.x * 256 + threadIdx.x) * 4;
#pragma unroll
    for (int j = 0; j < 4; j++) {
        unsigned short cv = c[i + j];
        u[i + j] = cv;
        a[i + j] = f2fp8(fmaxf(bf2f(cv) - 0.1f, 0.f) * 8.0f);
    }
}

// g = silu(g) * up  (bf16 in/out)
__global__ void swiglu_k(unsigned short* __restrict__ g, const unsigned short* __restrict__ u) {
    ll i = ((ll)blockIdx.x * 256 + threadIdx.x) * 4;
#pragma unroll
    for (int j = 0; j < 4; j++) {
        float x = bf2f(g[i + j]);
        float y = bf2f(u[i + j]);
        float sil = x / (1.0f + __expf(-x));
        g[i + j] = f2bf(sil * y);
    }
}

// ---------------- host orchestration ----------------
extern "C" void kernel_launch(void* const* d_in, const int* in_sizes, int n_in,
                              void* d_out, int out_size, void* d_ws, size_t ws_size,
                              hipStream_t stream) {
    (void)in_sizes; (void)n_in; (void)out_size; (void)ws_size;
    const float* X        = (const float*)d_in[0];
    const float* wln_in   = (const float*)d_in[1];
    const float* wln_lca  = (const float*)d_in[2];
    const float* wln_post = (const float*)d_in[3];
    const float* Wq   = (const float*)d_in[4];
    const float* Wk   = (const float*)d_in[5];
    const float* Wv   = (const float*)d_in[6];
    const float* Wo   = (const float*)d_in[7];
    const float* Wlca = (const float*)d_in[8];       // [2048,4096]
    const float* Wg   = (const float*)d_in[9];
    const float* Wu   = (const float*)d_in[10];
    const float* Wd   = (const float*)d_in[11];      // [8192,2048]
    float* out = (float*)d_out;

    char* ws = (char*)d_ws;
    unsigned short* WqT = (unsigned short*)(ws);
    unsigned short* WkT = WqT + 4194304;
    unsigned short* WvT = WqT + 2 * 4194304;
    unsigned short* WoT = WqT + 3 * 4194304;
    unsigned short* WgT = WqT;
    unsigned short* WlcaT = (unsigned short*)(ws + 33554432);  // [4096,2048] bf16
    unsigned short* Wlcab = WlcaT + 8388608;                   // [2048,4096] bf16
    unsigned short* WuT   = WlcaT;
    unsigned short* h_bf = (unsigned short*)(ws + 67108864);
    char* pool = ws + 83886080;
    // attention phase
    unsigned short* qb     = (unsigned short*)(pool);
    unsigned short* kb     = (unsigned short*)(pool + 16777216);
    unsigned short* vb     = (unsigned short*)(pool + 33554432);
    unsigned short* VT     = (unsigned short*)(pool + 50331648);
    unsigned short* attn   = (unsigned short*)(pool + 67108864);
    unsigned short* scores = (unsigned short*)(pool + 83886080);
    float* h1              = (float*)(pool + 150994944);
    // LCA phase
    unsigned short* cbuf   = (unsigned short*)(pool);               // 0.1*b bf16 (32MB)
    unsigned short* ubuf   = (unsigned short*)(pool + 33554432);    // u bf16 (32MB)
    unsigned char* a8_0    = (unsigned char*)(pool + 67108864);     // a fp8 x8 (16MB)
    unsigned char* a8_1    = (unsigned char*)(pool + 83886080);     // a fp8 x8 (16MB)
    unsigned short* abf    = (unsigned short*)(pool + 100663296);   // final a bf16 (32MB)
    unsigned char* Gf8     = (unsigned char*)(pool + 134217728);    // G*16 fp8 (16MB)
    float* h2              = (float*)(pool + 150994944);            // reuses h1 slot
    // MLP phase
    unsigned short* gate   = (unsigned short*)(pool);
    unsigned short* up     = (unsigned short*)(pool + 67108864);
    unsigned short* WdT    = (unsigned short*)(pool + 201326592);

    dim3 blk(256);
    auto gemm = [&](const unsigned short* A, ll lda, ll sAz,
                    const unsigned short* Bt, ll ldb, ll sBz,
                    void* C, ll ldc, ll sCz,
                    int M, int N, int K, int Z,
                    float alpha, int mode, int causal, const float* res) {
        dim3 g(N / 128, M / 128, Z);
        gemm_bf16<<<g, blk, 0, stream>>>(A, lda, sAz, Bt, ldb, sBz, C, ldc, sCz,
                                         M, N, K, alpha, mode, causal, res);
    };

    // --- weight prep ---
    wtrans_k<<<dim3(64, 64), blk, 0, stream>>>(Wq, WqT, 2048, 2048);
    wtrans_k<<<dim3(64, 64), blk, 0, stream>>>(Wk, WkT, 2048, 2048);
    wtrans_k<<<dim3(64, 64), blk, 0, stream>>>(Wv, WvT, 2048, 2048);
    wtrans_k<<<dim3(64, 64), blk, 0, stream>>>(Wo, WoT, 2048, 2048);
    wtrans_k<<<dim3(128, 64), blk, 0, stream>>>(Wlca, WlcaT, 2048, 4096);
    conv4_k<<<8192, blk, 0, stream>>>(Wlca, Wlcab, 8388608LL);

    // --- attention ---
    rmsnorm_k<<<4096, blk, 0, stream>>>(X, wln_in, h_bf);
    gemm(h_bf, 2048, 0, WqT, 2048, 0, qb, 2048, 0, 4096, 2048, 2048, 1, 1.f, 1, 0, nullptr);
    gemm(h_bf, 2048, 0, WkT, 2048, 0, kb, 2048, 0, 4096, 2048, 2048, 1, 1.f, 1, 0, nullptr);
    gemm(h_bf, 2048, 0, WvT, 2048, 0, vb, 2048, 0, 4096, 2048, 2048, 1, 1.f, 1, 0, nullptr);
    rope_k<<<16384, blk, 0, stream>>>(qb, kb);
    vtrans_k<<<dim3(4, 64, 32), blk, 0, stream>>>(vb, VT);
    for (int c = 0; c < 4; c++) {
        int b = c >> 1, h0 = (c & 1) * 8;
        const unsigned short* qbase = qb + (ll)b * 4194304 + h0 * 128;
        const unsigned short* kbase = kb + (ll)b * 4194304 + h0 * 128;
        gemm(qbase, 2048, 128, kbase, 2048, 128, scores, 2048, 4194304LL,
             2048, 2048, 128, 8, 0.08838834764831845f, 1, 1, nullptr);
        softmax_k<<<dim3(2048, 8), blk, 0, stream>>>(scores);
        const unsigned short* vtb = VT + (ll)(b * 16 + h0) * 262144;
        unsigned short* ab = attn + (ll)b * 4194304 + h0 * 128;
        gemm(scores, 2048, 4194304LL, vtb, 2048, 262144LL, ab, 2048, 128,
             2048, 128, 2048, 8, 1.f, 1, 0, nullptr);
    }
    gemm(attn, 2048, 0, WoT, 2048, 0, h1, 2048, 0, 4096, 2048, 2048, 1, 1.f, 0, 0, X);

    // --- LCA ---
    rmsnorm_k<<<4096, blk, 0, stream>>>(h1, wln_lca, h_bf);
    // G*16 in fp8 (zero diag):
    gemm(WlcaT, 2048, 0, WlcaT, 2048, 0, Gf8, 4096, 0, 4096, 4096, 2048, 1, 16.f, 2, 0, nullptr);
    // c = 0.1*b (bf16):
    gemm(h_bf, 2048, 0, WlcaT, 2048, 0, cbuf, 4096, 0, 4096, 4096, 2048, 1, 0.1f, 1, 0, nullptr);
    lca_init_k<<<16384, blk, 0, stream>>>(cbuf, ubuf, a8_0);
    unsigned char* acur = a8_0; unsigned char* anext = a8_1;
    for (int i = 0; i < 9; i++) {
        int mode = (i < 8) ? 3 : 4;
        void* outp = (i < 8) ? (void*)anext : (void*)abf;
        gemm_fp8<<<dim3(32, 32), blk, 0, stream>>>(
            acur, 4096, Gf8, 4096, 4096, 4096, 4096,
            0.1f / 128.0f, mode, ubuf, cbuf, outp);
        unsigned char* tmp = acur; acur = anext; anext = tmp;
    }
    gemm(abf, 4096, 0, Wlcab, 4096, 0, h2, 2048, 0, 4096, 2048, 4096, 1, 1.f, 0, 0, nullptr);

    // --- MLP ---
    wtrans_k<<<dim3(256, 64), blk, 0, stream>>>(Wg, WgT, 2048, 8192);
    wtrans_k<<<dim3(256, 64), blk, 0, stream>>>(Wu, WuT, 2048, 8192);
    wtrans_k<<<dim3(64, 256), blk, 0, stream>>>(Wd, WdT, 8192, 2048);
    rmsnorm_k<<<4096, blk, 0, stream>>>(h2, wln_post, h_bf);
    gemm(h_bf, 2048, 0, WgT, 2048, 0, gate, 8192, 0, 4096, 8192, 2048, 1, 1.f, 1, 0, nullptr);
    gemm(h_bf, 2048, 0, WuT, 2048, 0, up, 8192, 0, 4096, 8192, 2048, 1, 1.f, 1, 0, nullptr);
    swiglu_k<<<32768, blk, 0, stream>>>(gate, up);
    gemm(gate, 8192, 0, WdT, 8192, 0, out, 2048, 0, 4096, 2048, 8192, 1, 1.f, 0, 0, h2);
}